// Round 7
// baseline (727.036 us; speedup 1.0000x reference)
//
#include <hip/hip_runtime.h>

#define NQ 10
#define NSAMP 16384
#define BN_EPS 1e-5f

// -------- cross-lane xor shuffle --------
// masks < 0x20: single ds_swizzle_b32 immediate bit-mode (xor within 32 ==
// global xor for mask<32). masks >= 0x20: ds_bpermute with precomputed addr.
template<int M>
__device__ __forceinline__ float shufx(float v, int a30, int a28, int a20) {
  if constexpr (M < 32) {
    return __int_as_float(__builtin_amdgcn_ds_swizzle(
        __float_as_int(v), (M << 10) | 0x1F));
  } else {
    const int addr = (M == 0x30) ? a30 : (M == 0x28) ? a28 : a20;
    return __int_as_float(__builtin_amdgcn_ds_bpermute(addr, __float_as_int(v)));
  }
}

// -------- compile-time mask tables (deferred CNOT-chain permutation) --------
// Index bit b (9..0) = wire (9-b). Lane holds bits 9..4, regs bits 3..0.
// Stored array never permuted; after k chains L[P_k p] = S[p], P_k = C^{-k},
// C = I + N (bit-downshift). Trace-verified (R4): e9 -> {9,8,5,4,1,0},
// e4 -> {4,3,0}. Gate on logical b at layer l: partner = C^l e_b,
// hi-parity = row b of C^{-l}. Layer 0 folded into initial product state.
constexpr int ML_[3][10] = {
  {0x20,0x10,0x08,0x04,0x02,0x01, 0,   0,   0,   0},
  {0x30,0x18,0x0C,0x06,0x03,0x01, 0,   0,   0,   0},
  {0x28,0x14,0x0A,0x05,0x02,0x01, 0,   0,   0,   0}};
constexpr int MR_[3][10] = {
  {0,0,0,0,0,0,   0x8,0x4,0x2,0x1},
  {0,0,0,0,0,0x8, 0xC,0x6,0x3,0x1},
  {0,0,0,0,0x8,0x4,0xA,0x5,0x2,0x1}};
constexpr int HL_[3][10] = {
  {0x20,0x10,0x08,0x04,0x02,0x01, 0,   0,   0,   0},
  {0x20,0x30,0x38,0x3C,0x3E,0x3F, 0x3F,0x3F,0x3F,0x3F},
  {0x20,0x10,0x28,0x14,0x2A,0x15, 0x2A,0x15,0x2A,0x15}};
constexpr int HR_[3][10] = {
  {0,0,0,0,0,0, 0x8,0x4,0x2,0x1},
  {0,0,0,0,0,0, 0x8,0xC,0xE,0xF},
  {0,0,0,0,0,0, 0x8,0x4,0xA,0x5}};
// Epilogue: row b of C^{-3}, b=9-q -> bits {b,b+1,b+4,b+5,b+8,b+9} ∩ [0,9].
constexpr int EHL[10] = {0x20,0x30,0x18,0x0C,0x26,0x33,0x19,0x0C,0x26,0x33};
// reg-parity masks for q6..9: {0x8, 0xC, 0x6, 0x3}

constexpr int hibit4(int m) {
  return m >= 8 ? 8 : (m >= 4 ? 4 : (m >= 2 ? 2 : (m ? 1 : 0)));
}
constexpr bool par4(int v) { return ((v >> 3 & 1) ^ (v >> 2 & 1) ^ (v >> 1 & 1) ^ (v & 1)) != 0; }

// SU(2) gate [[w,-conj(v)],[v,conj(w)]], partner (ML lane, MR reg),
// hi-parity (HL lane, HR reg). sigma = hi ? +1 : -1:
//   sr' = wr*ar + sigma*wi*ai + sigma*vr*br - vi*bi
//   si' = wr*ai - sigma*wi*ar + sigma*vr*bi + vi*br
template<int ML, int MR, int HL, int HR>
__device__ __forceinline__ void gate(float* __restrict__ sr, float* __restrict__ si,
                                     int lane, int a30, int a28, int a20,
                                     float wr, float wi, float vr, float vi) {
  float swi, svr;  // coefficient values for reg-parity == 0
  if constexpr (HL != 0) {
    const bool lhi = (__builtin_popcount(lane & HL) & 1) != 0;
    swi = lhi ? wi : -wi;
    svr = lhi ? vr : -vr;
  } else {
    swi = -wi; svr = -vr;
  }
  if constexpr (MR == 0) {
    #pragma unroll
    for (int r = 0; r < 16; ++r) {
      float ar = sr[r], ai = si[r];
      float br = shufx<ML>(ar, a30, a28, a20);
      float bi = shufx<ML>(ai, a30, a28, a20);
      const float awi = par4(r & HR) ? -swi : swi;
      const float avr = par4(r & HR) ? -svr : svr;
      sr[r] = wr * ar + awi * ai + avr * br - vi * bi;
      si[r] = wr * ai - awi * ar + avr * bi + vi * br;
    }
  } else {
    constexpr int HB = hibit4(MR);
    #pragma unroll
    for (int r = 0; r < 16; ++r) {
      if (!(r & HB)) {
        const int r2 = r ^ MR;
        float a0r = sr[r],  a0i = si[r];
        float a1r = sr[r2], a1i = si[r2];
        float b0r, b0i, b1r, b1i;
        if constexpr (ML != 0) {
          b0r = shufx<ML>(a1r, a30, a28, a20);
          b0i = shufx<ML>(a1i, a30, a28, a20);
          b1r = shufx<ML>(a0r, a30, a28, a20);
          b1i = shufx<ML>(a0i, a30, a28, a20);
        } else {
          b0r = a1r; b0i = a1i; b1r = a0r; b1i = a0i;
        }
        {
          const float awi = par4(r & HR) ? -swi : swi;
          const float avr = par4(r & HR) ? -svr : svr;
          sr[r] = wr * a0r + awi * a0i + avr * b0r - vi * b0i;
          si[r] = wr * a0i - awi * a0r + avr * b0i + vi * b0r;
        }
        {
          const float awi = par4(r2 & HR) ? -swi : swi;
          const float avr = par4(r2 & HR) ? -svr : svr;
          sr[r2] = wr * a1r + awi * a1i + avr * b1r - vi * b1i;
          si[r2] = wr * a1i - awi * a1r + avr * b1i + vi * b1r;
        }
      }
    }
  }
}

template<int L, int Q>
__device__ __forceinline__ void rotg(const float4* __restrict__ cg,
                                     float* sr, float* si,
                                     int lane, int a30, int a28, int a20) {
  const float4 g = cg[L * 10 + Q];
  gate<ML_[L][Q], MR_[L][Q], HL_[L][Q], HR_[L][Q]>(
      sr, si, lane, a30, a28, a20, g.x, g.y, g.z, g.w);
}

// per-qubit encoded+layer0 2-vector: (alpha,beta) = U0q * (cos, sin)
__device__ __forceinline__ void enc2(const float4 g, float xq,
                                     float& ar, float& ai, float& br, float& bi) {
  float sq, cq;
  __sincosf(xq * 0.5f, &sq, &cq);
  ar = g.x * cq - g.z * sq;
  ai = g.y * cq + g.w * sq;
  br = g.z * cq + g.x * sq;
  bi = g.w * cq - g.y * sq;
}

__device__ __forceinline__ void cmul(float& zr, float& zi,
                                     float xr, float xi, float yr, float yi) {
  zr = xr * yr - xi * yi;
  zi = xr * yi + xi * yr;
}

// K0: 30 fused SU(2) matrices RY*RX*RZ from params (batch-uniform)
__global__ void coef_kernel(const float* __restrict__ params, float* __restrict__ coef) {
  int g = threadIdx.x;
  if (g < 30) {
    float t0 = params[g * 3 + 0] * 0.5f;
    float t1 = params[g * 3 + 1] * 0.5f;
    float t2 = params[g * 3 + 2] * 0.5f;
    float sa, ca, s2, c2, s3, c3;
    __sincosf(t0, &sa, &ca);
    __sincosf(t1, &s2, &c2);
    __sincosf(t2, &s3, &c3);
    float A = c3 * c2, Bv = s3 * s2, C = s3 * c2, D = c3 * s2;
    coef[g * 4 + 0] = A * ca + Bv * sa;      // wr
    coef[g * 4 + 1] = Bv * ca - A * sa;      // wi
    coef[g * 4 + 2] = C * ca - D * sa;       // vr
    coef[g * 4 + 3] = -(C * sa + D * ca);    // vi
  }
}

// K1: one wave64 per sample; 1024 amplitudes register-resident.
// Also block-reduces sum(e) / sum(e^2) into stats via atomics (fused BN pass 1).
__global__ __launch_bounds__(256, 8) void circuit_kernel(const float* __restrict__ x,
                                                         const float* __restrict__ coef,
                                                         float* __restrict__ out,
                                                         float* __restrict__ stats) {
  const int lane = threadIdx.x & 63;
  const int wv = threadIdx.x >> 6;
  const int wid = __builtin_amdgcn_readfirstlane(
      (int)((blockIdx.x * blockDim.x + threadIdx.x) >> 6));
  const float4* cg = (const float4*)coef;

  const int a30 = (lane ^ 0x30) << 2;
  const int a28 = (lane ^ 0x28) << 2;
  const int a20 = (lane ^ 0x20) << 2;

  // ---- encoding + layer-0 folded: progressive tensor-product build ----
  const float* xrow = x + wid * NQ;
  float lr, li;
  {
    float ar, ai, br, bi;
    enc2(cg[0], xrow[0], ar, ai, br, bi);
    lr = (lane & 32) ? br : ar;
    li = (lane & 32) ? bi : ai;
  }
  #pragma unroll
  for (int q = 1; q < 6; ++q) {
    float ar, ai, br, bi;
    enc2(cg[q], xrow[q], ar, ai, br, bi);
    const int bit = 1 << (5 - q);
    const float tr = (lane & bit) ? br : ar;
    const float ti = (lane & bit) ? bi : ai;
    const float nr = lr * tr - li * ti;
    const float ni = lr * ti + li * tr;
    lr = nr; li = ni;
  }
  float sr[16], si[16];
  {
    float ar, ai, br, bi;
    float t2r[2], t2i[2], t4r[4], t4i[4], t8r[8], t8i[8];
    enc2(cg[6], xrow[6], ar, ai, br, bi);
    cmul(t2r[0], t2i[0], lr, li, ar, ai);
    cmul(t2r[1], t2i[1], lr, li, br, bi);
    enc2(cg[7], xrow[7], ar, ai, br, bi);
    #pragma unroll
    for (int j = 0; j < 2; ++j) {
      cmul(t4r[2*j+0], t4i[2*j+0], t2r[j], t2i[j], ar, ai);
      cmul(t4r[2*j+1], t4i[2*j+1], t2r[j], t2i[j], br, bi);
    }
    enc2(cg[8], xrow[8], ar, ai, br, bi);
    #pragma unroll
    for (int j = 0; j < 4; ++j) {
      cmul(t8r[2*j+0], t8i[2*j+0], t4r[j], t4i[j], ar, ai);
      cmul(t8r[2*j+1], t8i[2*j+1], t4r[j], t4i[j], br, bi);
    }
    enc2(cg[9], xrow[9], ar, ai, br, bi);
    #pragma unroll
    for (int j = 0; j < 8; ++j) {
      cmul(sr[2*j+0], si[2*j+0], t8r[j], t8i[j], ar, ai);
      cmul(sr[2*j+1], si[2*j+1], t8r[j], t8i[j], br, bi);
    }
  }

  // ---- layers 1,2 fused rotations; CNOT chains free (index relabeling) ----
  rotg<1,0>(cg,sr,si,lane,a30,a28,a20); rotg<1,1>(cg,sr,si,lane,a30,a28,a20);
  rotg<1,2>(cg,sr,si,lane,a30,a28,a20); rotg<1,3>(cg,sr,si,lane,a30,a28,a20);
  rotg<1,4>(cg,sr,si,lane,a30,a28,a20); rotg<1,5>(cg,sr,si,lane,a30,a28,a20);
  rotg<1,6>(cg,sr,si,lane,a30,a28,a20); rotg<1,7>(cg,sr,si,lane,a30,a28,a20);
  rotg<1,8>(cg,sr,si,lane,a30,a28,a20); rotg<1,9>(cg,sr,si,lane,a30,a28,a20);

  rotg<2,0>(cg,sr,si,lane,a30,a28,a20); rotg<2,1>(cg,sr,si,lane,a30,a28,a20);
  rotg<2,2>(cg,sr,si,lane,a30,a28,a20); rotg<2,3>(cg,sr,si,lane,a30,a28,a20);
  rotg<2,4>(cg,sr,si,lane,a30,a28,a20); rotg<2,5>(cg,sr,si,lane,a30,a28,a20);
  rotg<2,6>(cg,sr,si,lane,a30,a28,a20); rotg<2,7>(cg,sr,si,lane,a30,a28,a20);
  rotg<2,8>(cg,sr,si,lane,a30,a28,a20); rotg<2,9>(cg,sr,si,lane,a30,a28,a20);

  // ---- <Z_q> epilogue: 5 on-the-fly Walsh sums (no p[16] array) ----
  float tot = 0.f, s8 = 0.f, sc = 0.f, s6 = 0.f, s3 = 0.f;
  #pragma unroll
  for (int r = 0; r < 16; ++r) {
    const float pr = sr[r] * sr[r] + si[r] * si[r];
    tot += pr;
    s8 = par4(r & 0x8) ? s8 - pr : s8 + pr;
    sc = par4(r & 0xC) ? sc - pr : sc + pr;
    s6 = par4(r & 0x6) ? s6 - pr : s6 + pr;
    s3 = par4(r & 0x3) ? s3 - pr : s3 + pr;
  }
  float e[10];
  #pragma unroll
  for (int q = 0; q < 6; ++q)
    e[q] = (__builtin_popcount(lane & EHL[q]) & 1) ? -tot : tot;
  e[6] = (__builtin_popcount(lane & EHL[6]) & 1) ? -s8 : s8;
  e[7] = (__builtin_popcount(lane & EHL[7]) & 1) ? -sc : sc;
  e[8] = (__builtin_popcount(lane & EHL[8]) & 1) ? -s6 : s6;
  e[9] = (__builtin_popcount(lane & EHL[9]) & 1) ? -s3 : s3;

  #pragma unroll
  for (int q = 0; q < 10; ++q) {
    e[q] += shufx<0x20>(e[q], a30, a28, a20);
    e[q] += shufx<0x10>(e[q], a30, a28, a20);
    e[q] += shufx<0x08>(e[q], a30, a28, a20);
    e[q] += shufx<0x04>(e[q], a30, a28, a20);
    e[q] += shufx<0x02>(e[q], a30, a28, a20);
    e[q] += shufx<0x01>(e[q], a30, a28, a20);
  }

  // ---- store + fused BN stats (block reduce -> 20 atomics/block) ----
  __shared__ float red[4][20];
  if (lane == 0) {
    #pragma unroll
    for (int q = 0; q < 10; ++q) {
      out[wid * NQ + q] = e[q];
      red[wv][q]      = e[q];
      red[wv][10 + q] = e[q] * e[q];
    }
  }
  __syncthreads();
  const int tid = threadIdx.x;
  if (tid < 20) {
    float ssum = red[0][tid] + red[1][tid] + red[2][tid] + red[3][tid];
    atomicAdd(&stats[tid], ssum);
  }
}

// K2: BatchNorm apply; finalizes mean/rstd from fused sums per thread.
__global__ __launch_bounds__(256) void bn_kernel(float* __restrict__ out,
                                                 const float* __restrict__ stats,
                                                 const float* __restrict__ gamma,
                                                 const float* __restrict__ beta) {
  int i = blockIdx.x * 256 + threadIdx.x;
  if (i < NSAMP * NQ) {
    int q = i % NQ;
    float mean = stats[q] * (1.f / NSAMP);
    float var = stats[10 + q] * (1.f / NSAMP) - mean * mean;
    if (var < 0.f) var = 0.f;
    float rstd = rsqrtf(var + BN_EPS);
    float v = out[i];
    out[i] = gamma[q] * (v - mean) * rstd + beta[q];
  }
}

extern "C" void kernel_launch(void* const* d_in, const int* in_sizes, int n_in,
                              void* d_out, int out_size, void* d_ws, size_t ws_size,
                              hipStream_t stream) {
  const float* x      = (const float*)d_in[0];
  const float* params = (const float*)d_in[1];
  const float* gamma  = (const float*)d_in[2];
  const float* beta   = (const float*)d_in[3];
  float* out = (float*)d_out;
  float* stats = (float*)d_ws;            // [0..9]=sum(e), [10..19]=sum(e^2)
  float* coef = (float*)d_ws + 32;        // 30 gates * 4 floats (16B aligned)

  hipMemsetAsync(stats, 0, 20 * sizeof(float), stream);  // zero accumulators each call
  coef_kernel<<<1, 32, 0, stream>>>(params, coef);
  circuit_kernel<<<NSAMP / 4, 256, 0, stream>>>(x, coef, out, stats);
  bn_kernel<<<(NSAMP * NQ + 255) / 256, 256, 0, stream>>>(out, stats, gamma, beta);
}

// Round 8
// 73.296 us; speedup vs baseline: 9.9192x; 9.9192x over previous
//
#include <hip/hip_runtime.h>

#define NQ 10
#define NSAMP 16384
#define BN_EPS 1e-5f

// ---------------- packed f16 helpers ----------------
typedef _Float16 h2 __attribute__((ext_vector_type(2)));
union H2U { h2 h; unsigned u; };
__device__ __forceinline__ h2 u2h(unsigned u) { H2U t; t.u = u; return t.h; }
__device__ __forceinline__ unsigned h2u(h2 h) { H2U t; t.h = h; return t.u; }
__device__ __forceinline__ h2 hswap(h2 x) {      // swap lo/hi halves (v_alignbit)
  unsigned u = h2u(x); return u2h((u >> 16) | (u << 16));
}
__device__ __forceinline__ h2 hpack(float lo, float hi) {
  h2 r; r.x = (_Float16)lo; r.y = (_Float16)hi; return r;
}

// masks < 0x20: ds_swizzle immediate xor; >= 0x20: ds_bpermute w/ precomputed addr
template<int M>
__device__ __forceinline__ unsigned shufu(unsigned v, int a30, int a28, int a20) {
  if constexpr (M < 32) {
    return (unsigned)__builtin_amdgcn_ds_swizzle((int)v, (M << 10) | 0x1F);
  } else {
    const int addr = (M == 0x30) ? a30 : (M == 0x28) ? a28 : a20;
    return (unsigned)__builtin_amdgcn_ds_bpermute(addr, (int)v);
  }
}
template<int M>
__device__ __forceinline__ h2 shufh(h2 v, int a30, int a28, int a20) {
  return u2h(shufu<M>(h2u(v), a30, a28, a20));
}
__device__ __forceinline__ float shuff(float v, int a30, int a28, int a20, int m) {
  (void)a30; (void)a28; (void)a20; (void)m; return v;  // unused
}

// -------- mask tables (deferred CNOT-chain relabeling) — trace-verified R4-R6 --------
// Index bit b (9..0) = wire (9-b). Lane holds bits 9..4, regs bits 3..0; reg
// amps packed as pairs (r, r|8) -> h2 Hr[8]/Hi[8] (lo = r<8, hi = r|8).
constexpr int ML_[3][10] = {
  {0x20,0x10,0x08,0x04,0x02,0x01, 0,   0,   0,   0},
  {0x30,0x18,0x0C,0x06,0x03,0x01, 0,   0,   0,   0},
  {0x28,0x14,0x0A,0x05,0x02,0x01, 0,   0,   0,   0}};
constexpr int MR_[3][10] = {
  {0,0,0,0,0,0,   0x8,0x4,0x2,0x1},
  {0,0,0,0,0,0x8, 0xC,0x6,0x3,0x1},
  {0,0,0,0,0x8,0x4,0xA,0x5,0x2,0x1}};
constexpr int HL_[3][10] = {
  {0x20,0x10,0x08,0x04,0x02,0x01, 0,   0,   0,   0},
  {0x20,0x30,0x38,0x3C,0x3E,0x3F, 0x3F,0x3F,0x3F,0x3F},
  {0x20,0x10,0x28,0x14,0x2A,0x15, 0x2A,0x15,0x2A,0x15}};
constexpr int HR_[3][10] = {
  {0,0,0,0,0,0, 0x8,0x4,0x2,0x1},
  {0,0,0,0,0,0, 0x8,0xC,0xE,0xF},
  {0,0,0,0,0,0, 0x8,0x4,0xA,0x5}};
// Epilogue sign masks (row b of C^{-3}), trace-verified in R4.
constexpr int EHL[10] = {0x20,0x30,0x18,0x0C,0x26,0x33,0x19,0x0C,0x26,0x33};

constexpr bool par4(int v) { return ((v >> 3 & 1) ^ (v >> 2 & 1) ^ (v >> 1 & 1) ^ (v & 1)) != 0; }

__device__ __forceinline__ void updh(h2& ar, h2& ai, h2 br, h2 bi,
                                     h2 WR, h2 AWI, h2 NAWI, h2 AVR, h2 VI, h2 NVI) {
  const h2 a0r = ar, a0i = ai;
  ar = WR * a0r + AWI * a0i + AVR * br + NVI * bi;
  ai = WR * a0i + NAWI * a0r + AVR * bi + VI * br;
}

// SU(2) gate on packed state. cp = packed (wr,wr),(wi,wi),(vr,vr),(vi,vi).
// sigma_r = lhi(lane,HL) ^ par4(r&HR); per-half handled via hif (HR bit3) and
// per-j compile-time variant selection (HR bits 2..0).
template<int ML, int MR, int HL, int HR>
__device__ __forceinline__ void gateh(h2* __restrict__ Hr, h2* __restrict__ Hi,
                                      int lane, int a30, int a28, int a20, uint4 cp) {
  const bool lhi = (HL != 0) && (__builtin_popcount(lane & HL) & 1);
  const unsigned swi = lhi ? cp.y : (cp.y ^ 0x80008000u);
  const unsigned svr = lhi ? cp.z : (cp.z ^ 0x80008000u);
  constexpr unsigned hif = (HR & 8) ? 0x80000000u : 0u;
  const h2 WR  = u2h(cp.x);
  const h2 VI  = u2h(cp.w);
  const h2 NVI = u2h(cp.w ^ 0x80008000u);
  const h2 WI0 = u2h(swi ^ hif);                  // awi for par=0
  const h2 WI1 = u2h(swi ^ hif ^ 0x80008000u);    // awi for par=1
  const h2 VR0 = u2h(svr ^ hif);
  const h2 VR1 = u2h(svr ^ hif ^ 0x80008000u);

  if constexpr (MR == 0) {                         // lane-bit gate
    #pragma unroll
    for (int j = 0; j < 8; ++j) {
      const h2 br = shufh<ML>(Hr[j], a30, a28, a20);
      const h2 bi = shufh<ML>(Hi[j], a30, a28, a20);
      const bool cp_ = par4(j & (HR & 7));
      updh(Hr[j], Hi[j], br, bi, WR, cp_ ? WI1 : WI0, cp_ ? WI0 : WI1,
           cp_ ? VR1 : VR0, VI, NVI);
    }
  } else if constexpr ((MR & 7) == 0) {            // reg bit3 (+ maybe lane)
    #pragma unroll
    for (int j = 0; j < 8; ++j) {
      h2 br = Hr[j], bi = Hi[j];
      if constexpr (ML != 0) { br = shufh<ML>(br, a30, a28, a20); bi = shufh<ML>(bi, a30, a28, a20); }
      br = hswap(br); bi = hswap(bi);
      const bool cp_ = par4(j & (HR & 7));
      updh(Hr[j], Hi[j], br, bi, WR, cp_ ? WI1 : WI0, cp_ ? WI0 : WI1,
           cp_ ? VR1 : VR0, VI, NVI);
    }
  } else {                                         // reg pair (+ maybe bit3, lane)
    constexpr int JX = MR & 7;
    constexpr int HB = (JX >= 4) ? 4 : (JX >= 2) ? 2 : 1;
    #pragma unroll
    for (int j = 0; j < 8; ++j) {
      if (!(j & HB)) {
        const int j2 = j ^ JX;
        h2 bra = Hr[j2], bia = Hi[j2], brb = Hr[j], bib = Hi[j];
        if constexpr (ML != 0) {
          bra = shufh<ML>(bra, a30, a28, a20); bia = shufh<ML>(bia, a30, a28, a20);
          brb = shufh<ML>(brb, a30, a28, a20); bib = shufh<ML>(bib, a30, a28, a20);
        }
        if constexpr ((MR & 8) != 0) {
          bra = hswap(bra); bia = hswap(bia); brb = hswap(brb); bib = hswap(bib);
        }
        const bool cpa = par4(j & (HR & 7));
        updh(Hr[j], Hi[j], bra, bia, WR, cpa ? WI1 : WI0, cpa ? WI0 : WI1,
             cpa ? VR1 : VR0, VI, NVI);
        const bool cpb = par4(j2 & (HR & 7));
        updh(Hr[j2], Hi[j2], brb, bib, WR, cpb ? WI1 : WI0, cpb ? WI0 : WI1,
             cpb ? VR1 : VR0, VI, NVI);
      }
    }
  }
}

template<int L, int Q>
__device__ __forceinline__ void rotgh(const uint4* __restrict__ cph, h2* Hr, h2* Hi,
                                      int lane, int a30, int a28, int a20) {
  const uint4 cp = cph[(L - 1) * 10 + Q];
  gateh<ML_[L][Q], MR_[L][Q], HL_[L][Q], HR_[L][Q]>(Hr, Hi, lane, a30, a28, a20, cp);
}

// per-qubit encoded+layer0 2-vector: (alpha,beta) = U0q * (cos, sin)
__device__ __forceinline__ void enc2(const float4 g, float xq,
                                     float& ar, float& ai, float& br, float& bi) {
  float sq, cq;
  __sincosf(xq * 0.5f, &sq, &cq);
  ar = g.x * cq - g.z * sq;
  ai = g.y * cq + g.w * sq;
  br = g.z * cq + g.x * sq;
  bi = g.w * cq - g.y * sq;
}
__device__ __forceinline__ void cmul(float& zr, float& zi,
                                     float xr, float xi, float yr, float yi) {
  zr = xr * yr - xi * yi;
  zi = xr * yi + xi * yr;
}

// K0: fused SU(2) RY*RX*RZ per (layer,qubit); f32 for layer0, packed for layers 1-2
__global__ void coef_kernel(const float* __restrict__ params, float* __restrict__ coef,
                            unsigned* __restrict__ cph) {
  int g = threadIdx.x;
  if (g < 30) {
    float t0 = params[g * 3 + 0] * 0.5f;
    float t1 = params[g * 3 + 1] * 0.5f;
    float t2 = params[g * 3 + 2] * 0.5f;
    float sa, ca, s2, c2, s3, c3;
    __sincosf(t0, &sa, &ca);
    __sincosf(t1, &s2, &c2);
    __sincosf(t2, &s3, &c3);
    float A = c3 * c2, Bv = s3 * s2, C = s3 * c2, D = c3 * s2;
    float wr = A * ca + Bv * sa;
    float wi = Bv * ca - A * sa;
    float vr = C * ca - D * sa;
    float vi = -(C * sa + D * ca);
    coef[g * 4 + 0] = wr;
    coef[g * 4 + 1] = wi;
    coef[g * 4 + 2] = vr;
    coef[g * 4 + 3] = vi;
    if (g >= 10) {
      int gi = g - 10;
      cph[gi * 4 + 0] = h2u(hpack(wr, wr));
      cph[gi * 4 + 1] = h2u(hpack(wi, wi));
      cph[gi * 4 + 2] = h2u(hpack(vr, vr));
      cph[gi * 4 + 3] = h2u(hpack(vi, vi));
    }
  }
}

// K1: one wave64 per sample; 1024 amps as 16 packed-f16 VGPRs; fused BN stats.
__global__ __launch_bounds__(256) void circuit_kernel(const float* __restrict__ x,
                                                      const float* __restrict__ coef,
                                                      const uint4* __restrict__ cph,
                                                      float* __restrict__ out,
                                                      float* __restrict__ stats) {
  const int lane = threadIdx.x & 63;
  const int wv = threadIdx.x >> 6;
  const int wid = __builtin_amdgcn_readfirstlane(
      (int)((blockIdx.x * blockDim.x + threadIdx.x) >> 6));
  const float4* cg = (const float4*)coef;

  const int a30 = (lane ^ 0x30) << 2;
  const int a28 = (lane ^ 0x28) << 2;
  const int a20 = (lane ^ 0x20) << 2;

  // ---- encoding + layer-0 folded: f32 progressive tensor-product build ----
  const float* xrow = x + wid * NQ;
  float lr, li;
  {
    float ar, ai, br, bi;
    enc2(cg[0], xrow[0], ar, ai, br, bi);
    lr = (lane & 32) ? br : ar;
    li = (lane & 32) ? bi : ai;
  }
  #pragma unroll
  for (int q = 1; q < 6; ++q) {
    float ar, ai, br, bi;
    enc2(cg[q], xrow[q], ar, ai, br, bi);
    const int bit = 1 << (5 - q);
    const float tr = (lane & bit) ? br : ar;
    const float ti = (lane & bit) ? bi : ai;
    const float nr = lr * tr - li * ti;
    const float ni = lr * ti + li * tr;
    lr = nr; li = ni;
  }
  float sr[16], si[16];
  {
    float ar, ai, br, bi;
    float t2r[2], t2i[2], t4r[4], t4i[4], t8r[8], t8i[8];
    enc2(cg[6], xrow[6], ar, ai, br, bi);
    cmul(t2r[0], t2i[0], lr, li, ar, ai);
    cmul(t2r[1], t2i[1], lr, li, br, bi);
    enc2(cg[7], xrow[7], ar, ai, br, bi);
    #pragma unroll
    for (int j = 0; j < 2; ++j) {
      cmul(t4r[2*j+0], t4i[2*j+0], t2r[j], t2i[j], ar, ai);
      cmul(t4r[2*j+1], t4i[2*j+1], t2r[j], t2i[j], br, bi);
    }
    enc2(cg[8], xrow[8], ar, ai, br, bi);
    #pragma unroll
    for (int j = 0; j < 4; ++j) {
      cmul(t8r[2*j+0], t8i[2*j+0], t4r[j], t4i[j], ar, ai);
      cmul(t8r[2*j+1], t8i[2*j+1], t4r[j], t4i[j], br, bi);
    }
    enc2(cg[9], xrow[9], ar, ai, br, bi);
    #pragma unroll
    for (int j = 0; j < 8; ++j) {
      cmul(sr[2*j+0], si[2*j+0], t8r[j], t8i[j], ar, ai);
      cmul(sr[2*j+1], si[2*j+1], t8r[j], t8i[j], br, bi);
    }
  }
  // pack pairs (r, r|8)
  h2 Hr[8], Hi[8];
  #pragma unroll
  for (int j = 0; j < 8; ++j) {
    Hr[j] = hpack(sr[j], sr[j | 8]);
    Hi[j] = hpack(si[j], si[j | 8]);
  }

  // ---- layers 1,2 fused rotations (packed); CNOT chains free ----
  rotgh<1,0>(cph,Hr,Hi,lane,a30,a28,a20); rotgh<1,1>(cph,Hr,Hi,lane,a30,a28,a20);
  rotgh<1,2>(cph,Hr,Hi,lane,a30,a28,a20); rotgh<1,3>(cph,Hr,Hi,lane,a30,a28,a20);
  rotgh<1,4>(cph,Hr,Hi,lane,a30,a28,a20); rotgh<1,5>(cph,Hr,Hi,lane,a30,a28,a20);
  rotgh<1,6>(cph,Hr,Hi,lane,a30,a28,a20); rotgh<1,7>(cph,Hr,Hi,lane,a30,a28,a20);
  rotgh<1,8>(cph,Hr,Hi,lane,a30,a28,a20); rotgh<1,9>(cph,Hr,Hi,lane,a30,a28,a20);

  rotgh<2,0>(cph,Hr,Hi,lane,a30,a28,a20); rotgh<2,1>(cph,Hr,Hi,lane,a30,a28,a20);
  rotgh<2,2>(cph,Hr,Hi,lane,a30,a28,a20); rotgh<2,3>(cph,Hr,Hi,lane,a30,a28,a20);
  rotgh<2,4>(cph,Hr,Hi,lane,a30,a28,a20); rotgh<2,5>(cph,Hr,Hi,lane,a30,a28,a20);
  rotgh<2,6>(cph,Hr,Hi,lane,a30,a28,a20); rotgh<2,7>(cph,Hr,Hi,lane,a30,a28,a20);
  rotgh<2,8>(cph,Hr,Hi,lane,a30,a28,a20); rotgh<2,9>(cph,Hr,Hi,lane,a30,a28,a20);

  // ---- packed epilogue: 4 packed Walsh accumulators ----
  h2 A0 = hpack(0.f, 0.f), A1 = A0, A2 = A0, A3 = A0;
  #pragma unroll
  for (int j = 0; j < 8; ++j) {
    const h2 P = Hr[j] * Hr[j] + Hi[j] * Hi[j];
    A0 = A0 + P;
    A1 = par4(j & 4) ? A1 - P : A1 + P;
    A2 = par4(j & 6) ? A2 - P : A2 + P;
    A3 = par4(j & 3) ? A3 - P : A3 + P;
  }
  const float tot = (float)A0.x + (float)A0.y;
  const float s8  = (float)A0.x - (float)A0.y;   // reg mask 0x8
  const float sc  = (float)A1.x - (float)A1.y;   // reg mask 0xC
  const float s6  = (float)A2.x + (float)A2.y;   // reg mask 0x6
  const float s3  = (float)A3.x + (float)A3.y;   // reg mask 0x3

  const float S[10] = {tot, tot, tot, tot, tot, tot, s8, sc, s6, s3};
  h2 E[5];
  #pragma unroll
  for (int k = 0; k < 5; ++k) {
    float ea = S[2 * k], eb = S[2 * k + 1];
    ea = (__builtin_popcount(lane & EHL[2 * k]) & 1) ? -ea : ea;
    eb = (__builtin_popcount(lane & EHL[2 * k + 1]) & 1) ? -eb : eb;
    E[k] = hpack(ea, eb);
  }
  #pragma unroll
  for (int k = 0; k < 5; ++k) {
    E[k] = E[k] + shufh<0x20>(E[k], a30, a28, a20);
    E[k] = E[k] + shufh<0x10>(E[k], a30, a28, a20);
    E[k] = E[k] + shufh<0x08>(E[k], a30, a28, a20);
    E[k] = E[k] + shufh<0x04>(E[k], a30, a28, a20);
    E[k] = E[k] + shufh<0x02>(E[k], a30, a28, a20);
    E[k] = E[k] + shufh<0x01>(E[k], a30, a28, a20);
  }

  // ---- store + fused BN stats (block reduce -> 20 atomics/block) ----
  __shared__ float red[4][20];
  if (lane == 0) {
    #pragma unroll
    for (int k = 0; k < 5; ++k) {
      const float ea = (float)E[k].x, eb = (float)E[k].y;
      out[wid * NQ + 2 * k]     = ea;
      out[wid * NQ + 2 * k + 1] = eb;
      red[wv][2 * k]          = ea;
      red[wv][2 * k + 1]      = eb;
      red[wv][10 + 2 * k]     = ea * ea;
      red[wv][10 + 2 * k + 1] = eb * eb;
    }
  }
  __syncthreads();
  const int tid = threadIdx.x;
  if (tid < 20) {
    float ssum = red[0][tid] + red[1][tid] + red[2][tid] + red[3][tid];
    atomicAdd(&stats[tid], ssum);
  }
}

// K2: BatchNorm apply; finalizes mean/rstd from fused sums per thread.
__global__ __launch_bounds__(256) void bn_kernel(float* __restrict__ out,
                                                 const float* __restrict__ stats,
                                                 const float* __restrict__ gamma,
                                                 const float* __restrict__ beta) {
  int i = blockIdx.x * 256 + threadIdx.x;
  if (i < NSAMP * NQ) {
    int q = i % NQ;
    float mean = stats[q] * (1.f / NSAMP);
    float var = stats[10 + q] * (1.f / NSAMP) - mean * mean;
    if (var < 0.f) var = 0.f;
    float rstd = rsqrtf(var + BN_EPS);
    float v = out[i];
    out[i] = gamma[q] * (v - mean) * rstd + beta[q];
  }
}

extern "C" void kernel_launch(void* const* d_in, const int* in_sizes, int n_in,
                              void* d_out, int out_size, void* d_ws, size_t ws_size,
                              hipStream_t stream) {
  const float* x      = (const float*)d_in[0];
  const float* params = (const float*)d_in[1];
  const float* gamma  = (const float*)d_in[2];
  const float* beta   = (const float*)d_in[3];
  float* out = (float*)d_out;
  float* stats = (float*)d_ws;                        // [0..9]=sum, [10..19]=sum^2
  float* coef = (float*)d_ws + 32;                    // 30 gates * 4 f32
  unsigned* cph = (unsigned*)((float*)d_ws + 160);    // 20 gates * 4 packed (16B-aligned)

  hipMemsetAsync(stats, 0, 20 * sizeof(float), stream);
  coef_kernel<<<1, 32, 0, stream>>>(params, coef, cph);
  circuit_kernel<<<NSAMP / 4, 256, 0, stream>>>(x, coef, (const uint4*)cph, out, stats);
  bn_kernel<<<(NSAMP * NQ + 255) / 256, 256, 0, stream>>>(out, stats, gamma, beta);
}

// Round 10
// 71.017 us; speedup vs baseline: 10.2375x; 1.0321x over previous
//
#include <hip/hip_runtime.h>

#define NQ 10
#define NSAMP 16384
#define BN_EPS 1e-5f

// ---------------- packed f16 helpers ----------------
typedef _Float16 h2 __attribute__((ext_vector_type(2)));
typedef __fp16 p16x2 __attribute__((ext_vector_type(2)));
union H2U { h2 h; unsigned u; p16x2 p; };
__device__ __forceinline__ h2 u2h(unsigned u) { H2U t; t.u = u; return t.h; }
__device__ __forceinline__ unsigned h2u(h2 h) { H2U t; t.h = h; return t.u; }
__device__ __forceinline__ h2 hswap(h2 x) {      // lo/hi swap; folds to op_sel/alignbit
  return __builtin_shufflevector(x, x, 1, 0);
}
__device__ __forceinline__ h2 hpack(float lo, float hi) {  // single v_cvt_pkrtz
  H2U t; t.p = __builtin_amdgcn_cvt_pkrtz(lo, hi);
  return t.h;
}

// masks < 0x20: ds_swizzle immediate xor; >= 0x20: ds_bpermute w/ precomputed addr
template<int M>
__device__ __forceinline__ unsigned shufu(unsigned v, int a30, int a28, int a20) {
  if constexpr (M < 32) {
    return (unsigned)__builtin_amdgcn_ds_swizzle((int)v, (M << 10) | 0x1F);
  } else {
    const int addr = (M == 0x30) ? a30 : (M == 0x28) ? a28 : a20;
    return (unsigned)__builtin_amdgcn_ds_bpermute(addr, (int)v);
  }
}
template<int M>
__device__ __forceinline__ h2 shufh(h2 v, int a30, int a28, int a20) {
  return u2h(shufu<M>(h2u(v), a30, a28, a20));
}

// -------- mask tables (deferred CNOT-chain relabeling) — trace-verified R4-R8 --------
// Index bit b (9..0) = wire (9-b). Lane holds bits 9..4, regs bits 3..0; reg
// amps packed as pairs (r, r|8) -> h2 Hr[8]/Hi[8] (lo = r<8, hi = r|8).
constexpr int ML_[3][10] = {
  {0x20,0x10,0x08,0x04,0x02,0x01, 0,   0,   0,   0},
  {0x30,0x18,0x0C,0x06,0x03,0x01, 0,   0,   0,   0},
  {0x28,0x14,0x0A,0x05,0x02,0x01, 0,   0,   0,   0}};
constexpr int MR_[3][10] = {
  {0,0,0,0,0,0,   0x8,0x4,0x2,0x1},
  {0,0,0,0,0,0x8, 0xC,0x6,0x3,0x1},
  {0,0,0,0,0x8,0x4,0xA,0x5,0x2,0x1}};
constexpr int HL_[3][10] = {
  {0x20,0x10,0x08,0x04,0x02,0x01, 0,   0,   0,   0},
  {0x20,0x30,0x38,0x3C,0x3E,0x3F, 0x3F,0x3F,0x3F,0x3F},
  {0x20,0x10,0x28,0x14,0x2A,0x15, 0x2A,0x15,0x2A,0x15}};
constexpr int HR_[3][10] = {
  {0,0,0,0,0,0, 0x8,0x4,0x2,0x1},
  {0,0,0,0,0,0, 0x8,0xC,0xE,0xF},
  {0,0,0,0,0,0, 0x8,0x4,0xA,0x5}};
// Epilogue sign masks (row b of C^{-3}), trace-verified in R4.
constexpr int EHL[10] = {0x20,0x30,0x18,0x0C,0x26,0x33,0x19,0x0C,0x26,0x33};

// distinct HL masks for layers 1,2 -> precomputed sign-word index
constexpr int SMASK[12] = {0x20,0x30,0x38,0x3C,0x3E,0x3F, 0x20,0x10,0x28,0x14,0x2A,0x15};
constexpr int SIX[2][10] = {{0,1,2,3,4,5,5,5,5,5}, {6,7,8,9,10,11,10,11,10,11}};

constexpr bool par4(int v) { return ((v >> 3 & 1) ^ (v >> 2 & 1) ^ (v >> 1 & 1) ^ (v & 1)) != 0; }

__device__ __forceinline__ void updh(h2& ar, h2& ai, h2 br, h2 bi,
                                     h2 WR, h2 AWI, h2 NAWI, h2 AVR, h2 VI, h2 NVI) {
  const h2 a0r = ar, a0i = ai;
  ar = WR * a0r + AWI * a0i + AVR * br + NVI * bi;
  ai = WR * a0i + NAWI * a0r + AVR * bi + VI * br;
}

// SU(2) gate on packed state. cp = packed (wr,wr),(wi,wi),(vr,vr),(vi,vi).
// sgnw = precomputed lane-parity sign word (0 if hi-parity lane, else 0x80008000).
template<int ML, int MR, int HR>
__device__ __forceinline__ void gateh(h2* __restrict__ Hr, h2* __restrict__ Hi,
                                      unsigned sgnw, int a30, int a28, int a20, uint4 cp) {
  const unsigned swi = cp.y ^ sgnw;
  const unsigned svr = cp.z ^ sgnw;
  constexpr unsigned hif = (HR & 8) ? 0x80000000u : 0u;
  const h2 WR  = u2h(cp.x);
  const h2 VI  = u2h(cp.w);
  const h2 NVI = u2h(cp.w ^ 0x80008000u);
  const h2 WI0 = u2h(swi ^ hif);                  // awi for par=0
  const h2 WI1 = u2h(swi ^ hif ^ 0x80008000u);    // awi for par=1
  const h2 VR0 = u2h(svr ^ hif);
  const h2 VR1 = u2h(svr ^ hif ^ 0x80008000u);

  if constexpr (MR == 0) {                         // lane-bit gate
    #pragma unroll
    for (int j = 0; j < 8; ++j) {
      const h2 br = shufh<ML>(Hr[j], a30, a28, a20);
      const h2 bi = shufh<ML>(Hi[j], a30, a28, a20);
      const bool cp_ = par4(j & (HR & 7));
      updh(Hr[j], Hi[j], br, bi, WR, cp_ ? WI1 : WI0, cp_ ? WI0 : WI1,
           cp_ ? VR1 : VR0, VI, NVI);
    }
  } else if constexpr ((MR & 7) == 0) {            // reg bit3 (+ maybe lane)
    #pragma unroll
    for (int j = 0; j < 8; ++j) {
      h2 br = Hr[j], bi = Hi[j];
      if constexpr (ML != 0) { br = shufh<ML>(br, a30, a28, a20); bi = shufh<ML>(bi, a30, a28, a20); }
      br = hswap(br); bi = hswap(bi);
      const bool cp_ = par4(j & (HR & 7));
      updh(Hr[j], Hi[j], br, bi, WR, cp_ ? WI1 : WI0, cp_ ? WI0 : WI1,
           cp_ ? VR1 : VR0, VI, NVI);
    }
  } else {                                         // reg pair (+ maybe bit3, lane)
    constexpr int JX = MR & 7;
    constexpr int HB = (JX >= 4) ? 4 : (JX >= 2) ? 2 : 1;
    #pragma unroll
    for (int j = 0; j < 8; ++j) {
      if (!(j & HB)) {
        const int j2 = j ^ JX;
        h2 bra = Hr[j2], bia = Hi[j2], brb = Hr[j], bib = Hi[j];
        if constexpr (ML != 0) {
          bra = shufh<ML>(bra, a30, a28, a20); bia = shufh<ML>(bia, a30, a28, a20);
          brb = shufh<ML>(brb, a30, a28, a20); bib = shufh<ML>(bib, a30, a28, a20);
        }
        if constexpr ((MR & 8) != 0) {
          bra = hswap(bra); bia = hswap(bia); brb = hswap(brb); bib = hswap(bib);
        }
        const bool cpa = par4(j & (HR & 7));
        updh(Hr[j], Hi[j], bra, bia, WR, cpa ? WI1 : WI0, cpa ? WI0 : WI1,
             cpa ? VR1 : VR0, VI, NVI);
        const bool cpb = par4(j2 & (HR & 7));
        updh(Hr[j2], Hi[j2], brb, bib, WR, cpb ? WI1 : WI0, cpb ? WI0 : WI1,
             cpb ? VR1 : VR0, VI, NVI);
      }
    }
  }
}

template<int L, int Q>
__device__ __forceinline__ void rotgh(const uint4* __restrict__ cph, h2* Hr, h2* Hi,
                                      const unsigned* __restrict__ sgnv,
                                      int a30, int a28, int a20) {
  const uint4 cp = cph[(L - 1) * 10 + Q];
  gateh<ML_[L][Q], MR_[L][Q], HR_[L][Q]>(Hr, Hi, sgnv[SIX[L - 1][Q]], a30, a28, a20, cp);
}

// per-qubit encoded+layer0 2-vector: (alpha,beta) = U0q * (cos, sin)
__device__ __forceinline__ void enc2(const float4 g, float xq,
                                     float& ar, float& ai, float& br, float& bi) {
  float sq, cq;
  __sincosf(xq * 0.5f, &sq, &cq);
  ar = g.x * cq - g.z * sq;
  ai = g.y * cq + g.w * sq;
  br = g.z * cq + g.x * sq;
  bi = g.w * cq - g.y * sq;
}
__device__ __forceinline__ void cmul(float& zr, float& zi,
                                     float xr, float xi, float yr, float yi) {
  zr = xr * yr - xi * yi;
  zi = xr * yi + xi * yr;
}

// K0: fused SU(2) RY*RX*RZ per (layer,qubit); also zeroes the stats accumulators
__global__ void coef_kernel(const float* __restrict__ params, float* __restrict__ coef,
                            unsigned* __restrict__ cph, float* __restrict__ stats) {
  int g = threadIdx.x;
  if (g < 20) stats[g] = 0.f;
  if (g < 30) {
    float t0 = params[g * 3 + 0] * 0.5f;
    float t1 = params[g * 3 + 1] * 0.5f;
    float t2 = params[g * 3 + 2] * 0.5f;
    float sa, ca, s2, c2, s3, c3;
    __sincosf(t0, &sa, &ca);
    __sincosf(t1, &s2, &c2);
    __sincosf(t2, &s3, &c3);
    float A = c3 * c2, Bv = s3 * s2, C = s3 * c2, D = c3 * s2;
    float wr = A * ca + Bv * sa;
    float wi = Bv * ca - A * sa;
    float vr = C * ca - D * sa;
    float vi = -(C * sa + D * ca);
    coef[g * 4 + 0] = wr;
    coef[g * 4 + 1] = wi;
    coef[g * 4 + 2] = vr;
    coef[g * 4 + 3] = vi;
    if (g >= 10) {
      int gi = g - 10;
      cph[gi * 4 + 0] = h2u(hpack(wr, wr));
      cph[gi * 4 + 1] = h2u(hpack(wi, wi));
      cph[gi * 4 + 2] = h2u(hpack(vr, vr));
      cph[gi * 4 + 3] = h2u(hpack(vi, vi));
    }
  }
}

// K1: one wave64 per sample; 1024 amps as 16 packed-f16 VGPRs; fused BN stats.
__global__ __launch_bounds__(256) void circuit_kernel(const float* __restrict__ x,
                                                      const float* __restrict__ coef,
                                                      const uint4* __restrict__ cph,
                                                      float* __restrict__ out,
                                                      float* __restrict__ stats) {
  const int lane = threadIdx.x & 63;
  const int wv = threadIdx.x >> 6;
  const int wid = __builtin_amdgcn_readfirstlane(
      (int)((blockIdx.x * blockDim.x + threadIdx.x) >> 6));
  const float4* cg = (const float4*)coef;

  const int a30 = (lane ^ 0x30) << 2;
  const int a28 = (lane ^ 0x28) << 2;
  const int a20 = (lane ^ 0x20) << 2;

  // precomputed lane-parity sign words for the 12 distinct HL masks
  unsigned sgnv[12];
  #pragma unroll
  for (int k = 0; k < 12; ++k)
    sgnv[k] = (__builtin_popcount(lane & SMASK[k]) & 1) ? 0u : 0x80008000u;

  // ---- encoding + layer-0 folded: f32 progressive tensor-product build ----
  const float* xrow = x + wid * NQ;
  float lr, li;
  {
    float ar, ai, br, bi;
    enc2(cg[0], xrow[0], ar, ai, br, bi);
    lr = (lane & 32) ? br : ar;
    li = (lane & 32) ? bi : ai;
  }
  #pragma unroll
  for (int q = 1; q < 6; ++q) {
    float ar, ai, br, bi;
    enc2(cg[q], xrow[q], ar, ai, br, bi);
    const int bit = 1 << (5 - q);
    const float tr = (lane & bit) ? br : ar;
    const float ti = (lane & bit) ? bi : ai;
    const float nr = lr * tr - li * ti;
    const float ni = lr * ti + li * tr;
    lr = nr; li = ni;
  }
  float sr[16], si[16];
  {
    float ar, ai, br, bi;
    float t2r[2], t2i[2], t4r[4], t4i[4], t8r[8], t8i[8];
    enc2(cg[6], xrow[6], ar, ai, br, bi);
    cmul(t2r[0], t2i[0], lr, li, ar, ai);
    cmul(t2r[1], t2i[1], lr, li, br, bi);
    enc2(cg[7], xrow[7], ar, ai, br, bi);
    #pragma unroll
    for (int j = 0; j < 2; ++j) {
      cmul(t4r[2*j+0], t4i[2*j+0], t2r[j], t2i[j], ar, ai);
      cmul(t4r[2*j+1], t4i[2*j+1], t2r[j], t2i[j], br, bi);
    }
    enc2(cg[8], xrow[8], ar, ai, br, bi);
    #pragma unroll
    for (int j = 0; j < 4; ++j) {
      cmul(t8r[2*j+0], t8i[2*j+0], t4r[j], t4i[j], ar, ai);
      cmul(t8r[2*j+1], t8i[2*j+1], t4r[j], t4i[j], br, bi);
    }
    enc2(cg[9], xrow[9], ar, ai, br, bi);
    #pragma unroll
    for (int j = 0; j < 8; ++j) {
      cmul(sr[2*j+0], si[2*j+0], t8r[j], t8i[j], ar, ai);
      cmul(sr[2*j+1], si[2*j+1], t8r[j], t8i[j], br, bi);
    }
  }
  // pack pairs (r, r|8)
  h2 Hr[8], Hi[8];
  #pragma unroll
  for (int j = 0; j < 8; ++j) {
    Hr[j] = hpack(sr[j], sr[j | 8]);
    Hi[j] = hpack(si[j], si[j | 8]);
  }

  // ---- layers 1,2 fused rotations (packed); CNOT chains free ----
  rotgh<1,0>(cph,Hr,Hi,sgnv,a30,a28,a20); rotgh<1,1>(cph,Hr,Hi,sgnv,a30,a28,a20);
  rotgh<1,2>(cph,Hr,Hi,sgnv,a30,a28,a20); rotgh<1,3>(cph,Hr,Hi,sgnv,a30,a28,a20);
  rotgh<1,4>(cph,Hr,Hi,sgnv,a30,a28,a20); rotgh<1,5>(cph,Hr,Hi,sgnv,a30,a28,a20);
  rotgh<1,6>(cph,Hr,Hi,sgnv,a30,a28,a20); rotgh<1,7>(cph,Hr,Hi,sgnv,a30,a28,a20);
  rotgh<1,8>(cph,Hr,Hi,sgnv,a30,a28,a20); rotgh<1,9>(cph,Hr,Hi,sgnv,a30,a28,a20);

  rotgh<2,0>(cph,Hr,Hi,sgnv,a30,a28,a20); rotgh<2,1>(cph,Hr,Hi,sgnv,a30,a28,a20);
  rotgh<2,2>(cph,Hr,Hi,sgnv,a30,a28,a20); rotgh<2,3>(cph,Hr,Hi,sgnv,a30,a28,a20);
  rotgh<2,4>(cph,Hr,Hi,sgnv,a30,a28,a20); rotgh<2,5>(cph,Hr,Hi,sgnv,a30,a28,a20);
  rotgh<2,6>(cph,Hr,Hi,sgnv,a30,a28,a20); rotgh<2,7>(cph,Hr,Hi,sgnv,a30,a28,a20);
  rotgh<2,8>(cph,Hr,Hi,sgnv,a30,a28,a20); rotgh<2,9>(cph,Hr,Hi,sgnv,a30,a28,a20);

  // ---- packed epilogue: 4 packed Walsh accumulators ----
  h2 A0 = hpack(0.f, 0.f), A1 = A0, A2 = A0, A3 = A0;
  #pragma unroll
  for (int j = 0; j < 8; ++j) {
    const h2 P = Hr[j] * Hr[j] + Hi[j] * Hi[j];
    A0 = A0 + P;
    A1 = par4(j & 4) ? A1 - P : A1 + P;
    A2 = par4(j & 6) ? A2 - P : A2 + P;
    A3 = par4(j & 3) ? A3 - P : A3 + P;
  }
  const float tot = (float)A0.x + (float)A0.y;
  const float s8  = (float)A0.x - (float)A0.y;   // reg mask 0x8
  const float sc  = (float)A1.x - (float)A1.y;   // reg mask 0xC
  const float s6  = (float)A2.x + (float)A2.y;   // reg mask 0x6
  const float s3  = (float)A3.x + (float)A3.y;   // reg mask 0x3

  const float S[10] = {tot, tot, tot, tot, tot, tot, s8, sc, s6, s3};
  h2 E[5];
  #pragma unroll
  for (int k = 0; k < 5; ++k) {
    float ea = S[2 * k], eb = S[2 * k + 1];
    ea = (__builtin_popcount(lane & EHL[2 * k]) & 1) ? -ea : ea;
    eb = (__builtin_popcount(lane & EHL[2 * k + 1]) & 1) ? -eb : eb;
    E[k] = hpack(ea, eb);
  }
  #pragma unroll
  for (int k = 0; k < 5; ++k) {
    E[k] = E[k] + shufh<0x20>(E[k], a30, a28, a20);
    E[k] = E[k] + shufh<0x10>(E[k], a30, a28, a20);
    E[k] = E[k] + shufh<0x08>(E[k], a30, a28, a20);
    E[k] = E[k] + shufh<0x04>(E[k], a30, a28, a20);
    E[k] = E[k] + shufh<0x02>(E[k], a30, a28, a20);
    E[k] = E[k] + shufh<0x01>(E[k], a30, a28, a20);
  }

  // ---- store + fused BN stats (block reduce -> 20 atomics/block) ----
  __shared__ float red[4][20];
  if (lane == 0) {
    #pragma unroll
    for (int k = 0; k < 5; ++k) {
      const float ea = (float)E[k].x, eb = (float)E[k].y;
      out[wid * NQ + 2 * k]     = ea;
      out[wid * NQ + 2 * k + 1] = eb;
      red[wv][2 * k]          = ea;
      red[wv][2 * k + 1]      = eb;
      red[wv][10 + 2 * k]     = ea * ea;
      red[wv][10 + 2 * k + 1] = eb * eb;
    }
  }
  __syncthreads();
  const int tid = threadIdx.x;
  if (tid < 20) {
    float ssum = red[0][tid] + red[1][tid] + red[2][tid] + red[3][tid];
    atomicAdd(&stats[tid], ssum);
  }
}

// K2: BatchNorm apply; finalizes mean/rstd from fused sums per thread.
__global__ __launch_bounds__(256) void bn_kernel(float* __restrict__ out,
                                                 const float* __restrict__ stats,
                                                 const float* __restrict__ gamma,
                                                 const float* __restrict__ beta) {
  int i = blockIdx.x * 256 + threadIdx.x;
  if (i < NSAMP * NQ) {
    int q = i % NQ;
    float mean = stats[q] * (1.f / NSAMP);
    float var = stats[10 + q] * (1.f / NSAMP) - mean * mean;
    if (var < 0.f) var = 0.f;
    float rstd = rsqrtf(var + BN_EPS);
    float v = out[i];
    out[i] = gamma[q] * (v - mean) * rstd + beta[q];
  }
}

extern "C" void kernel_launch(void* const* d_in, const int* in_sizes, int n_in,
                              void* d_out, int out_size, void* d_ws, size_t ws_size,
                              hipStream_t stream) {
  const float* x      = (const float*)d_in[0];
  const float* params = (const float*)d_in[1];
  const float* gamma  = (const float*)d_in[2];
  const float* beta   = (const float*)d_in[3];
  float* out = (float*)d_out;
  float* stats = (float*)d_ws;                        // [0..9]=sum, [10..19]=sum^2
  float* coef = (float*)d_ws + 32;                    // 30 gates * 4 f32
  unsigned* cph = (unsigned*)((float*)d_ws + 160);    // 20 gates * 4 packed (16B-aligned)

  coef_kernel<<<1, 32, 0, stream>>>(params, coef, cph, stats);
  circuit_kernel<<<NSAMP / 4, 256, 0, stream>>>(x, coef, (const uint4*)cph, out, stats);
  bn_kernel<<<(NSAMP * NQ + 255) / 256, 256, 0, stream>>>(out, stats, gamma, beta);
}

// Round 11
// 70.932 us; speedup vs baseline: 10.2497x; 1.0012x over previous
//
#include <hip/hip_runtime.h>
#include <hip/hip_fp16.h>

#define NQ 10
#define NSAMP 16384
#define BN_EPS 1e-5f

// ---------------- packed f16 helpers (__half2 -> guaranteed v_pk_* ops) ----------------
union H2U { __half2 h; unsigned u; };
__device__ __forceinline__ __half2 u2h(unsigned u) { H2U t; t.u = u; return t.h; }
__device__ __forceinline__ unsigned h2u(__half2 h) { H2U t; t.h = h; return t.u; }
__device__ __forceinline__ __half2 hswap(__half2 x) { return __lowhigh2highlow(x); }
__device__ __forceinline__ __half2 hpack(float lo, float hi) {
  return __floats2half2_rn(lo, hi);
}

// masks < 0x20: ds_swizzle immediate xor; >= 0x20: ds_bpermute w/ precomputed addr
template<int M>
__device__ __forceinline__ unsigned shufu(unsigned v, int a30, int a28, int a20) {
  if constexpr (M < 32) {
    return (unsigned)__builtin_amdgcn_ds_swizzle((int)v, (M << 10) | 0x1F);
  } else {
    const int addr = (M == 0x30) ? a30 : (M == 0x28) ? a28 : a20;
    return (unsigned)__builtin_amdgcn_ds_bpermute(addr, (int)v);
  }
}
template<int M>
__device__ __forceinline__ __half2 shufh(__half2 v, int a30, int a28, int a20) {
  return u2h(shufu<M>(h2u(v), a30, a28, a20));
}

// -------- mask tables (deferred CNOT-chain relabeling) — trace-verified R4-R10 --------
// Index bit b (9..0) = wire (9-b). Lane holds bits 9..4, regs bits 3..0; reg
// amps packed as pairs (r, r|8) -> __half2 Hr[8]/Hi[8] (lo = r<8, hi = r|8).
constexpr int ML_[3][10] = {
  {0x20,0x10,0x08,0x04,0x02,0x01, 0,   0,   0,   0},
  {0x30,0x18,0x0C,0x06,0x03,0x01, 0,   0,   0,   0},
  {0x28,0x14,0x0A,0x05,0x02,0x01, 0,   0,   0,   0}};
constexpr int MR_[3][10] = {
  {0,0,0,0,0,0,   0x8,0x4,0x2,0x1},
  {0,0,0,0,0,0x8, 0xC,0x6,0x3,0x1},
  {0,0,0,0,0x8,0x4,0xA,0x5,0x2,0x1}};
constexpr int HR_[3][10] = {
  {0,0,0,0,0,0, 0x8,0x4,0x2,0x1},
  {0,0,0,0,0,0, 0x8,0xC,0xE,0xF},
  {0,0,0,0,0,0, 0x8,0x4,0xA,0x5}};
// Epilogue sign masks (row b of C^{-3}), trace-verified in R4.
constexpr int EHL[10] = {0x20,0x30,0x18,0x0C,0x26,0x33,0x19,0x0C,0x26,0x33};

// distinct HL masks for layers 1,2 -> precomputed sign-word index
constexpr int SMASK[12] = {0x20,0x30,0x38,0x3C,0x3E,0x3F, 0x20,0x10,0x28,0x14,0x2A,0x15};
constexpr int SIX[2][10] = {{0,1,2,3,4,5,5,5,5,5}, {6,7,8,9,10,11,10,11,10,11}};

constexpr bool par4(int v) { return ((v >> 3 & 1) ^ (v >> 2 & 1) ^ (v >> 1 & 1) ^ (v & 1)) != 0; }

// amp update: 4 pk-FMA for re, 4 for im
__device__ __forceinline__ void updh(__half2& ar, __half2& ai, __half2 br, __half2 bi,
                                     __half2 WR, __half2 AWI, __half2 NAWI,
                                     __half2 AVR, __half2 VI, __half2 NVI) {
  const __half2 a0r = ar, a0i = ai;
  ar = __hfma2(WR, a0r, __hfma2(AWI, a0i, __hfma2(AVR, br, __hmul2(NVI, bi))));
  ai = __hfma2(WR, a0i, __hfma2(NAWI, a0r, __hfma2(AVR, bi, __hmul2(VI, br))));
}

// SU(2) gate on packed state. cp = packed (wr,wr),(wi,wi),(vr,vr),(vi,vi).
// sgnw = precomputed lane-parity sign word (0 if hi-parity lane, else 0x80008000).
template<int ML, int MR, int HR>
__device__ __forceinline__ void gateh(__half2* __restrict__ Hr, __half2* __restrict__ Hi,
                                      unsigned sgnw, int a30, int a28, int a20, uint4 cp) {
  const unsigned swi = cp.y ^ sgnw;
  const unsigned svr = cp.z ^ sgnw;
  constexpr unsigned hif = (HR & 8) ? 0x80000000u : 0u;
  const __half2 WR  = u2h(cp.x);
  const __half2 VI  = u2h(cp.w);
  const __half2 NVI = u2h(cp.w ^ 0x80008000u);
  const __half2 WI0 = u2h(swi ^ hif);                  // awi for par=0
  const __half2 WI1 = u2h(swi ^ hif ^ 0x80008000u);    // awi for par=1
  const __half2 NWI0 = WI1, NWI1 = WI0;
  const __half2 VR0 = u2h(svr ^ hif);
  const __half2 VR1 = u2h(svr ^ hif ^ 0x80008000u);

  if constexpr (MR == 0) {                         // lane-bit gate
    #pragma unroll
    for (int j = 0; j < 8; ++j) {
      const __half2 br = shufh<ML>(Hr[j], a30, a28, a20);
      const __half2 bi = shufh<ML>(Hi[j], a30, a28, a20);
      const bool cp_ = par4(j & (HR & 7));
      updh(Hr[j], Hi[j], br, bi, WR, cp_ ? WI1 : WI0, cp_ ? NWI1 : NWI0,
           cp_ ? VR1 : VR0, VI, NVI);
    }
  } else if constexpr ((MR & 7) == 0) {            // reg bit3 (+ maybe lane)
    #pragma unroll
    for (int j = 0; j < 8; ++j) {
      __half2 br = Hr[j], bi = Hi[j];
      if constexpr (ML != 0) { br = shufh<ML>(br, a30, a28, a20); bi = shufh<ML>(bi, a30, a28, a20); }
      br = hswap(br); bi = hswap(bi);
      const bool cp_ = par4(j & (HR & 7));
      updh(Hr[j], Hi[j], br, bi, WR, cp_ ? WI1 : WI0, cp_ ? NWI1 : NWI0,
           cp_ ? VR1 : VR0, VI, NVI);
    }
  } else {                                         // reg pair (+ maybe bit3, lane)
    constexpr int JX = MR & 7;
    constexpr int HB = (JX >= 4) ? 4 : (JX >= 2) ? 2 : 1;
    #pragma unroll
    for (int j = 0; j < 8; ++j) {
      if (!(j & HB)) {
        const int j2 = j ^ JX;
        __half2 bra = Hr[j2], bia = Hi[j2], brb = Hr[j], bib = Hi[j];
        if constexpr (ML != 0) {
          bra = shufh<ML>(bra, a30, a28, a20); bia = shufh<ML>(bia, a30, a28, a20);
          brb = shufh<ML>(brb, a30, a28, a20); bib = shufh<ML>(bib, a30, a28, a20);
        }
        if constexpr ((MR & 8) != 0) {
          bra = hswap(bra); bia = hswap(bia); brb = hswap(brb); bib = hswap(bib);
        }
        const bool cpa = par4(j & (HR & 7));
        updh(Hr[j], Hi[j], bra, bia, WR, cpa ? WI1 : WI0, cpa ? NWI1 : NWI0,
             cpa ? VR1 : VR0, VI, NVI);
        const bool cpb = par4(j2 & (HR & 7));
        updh(Hr[j2], Hi[j2], brb, bib, WR, cpb ? WI1 : WI0, cpb ? NWI1 : NWI0,
             cpb ? VR1 : VR0, VI, NVI);
      }
    }
  }
}

template<int L, int Q>
__device__ __forceinline__ void rotgh(const uint4* __restrict__ cph, __half2* Hr, __half2* Hi,
                                      const unsigned* __restrict__ sgnv,
                                      int a30, int a28, int a20) {
  const uint4 cp = cph[(L - 1) * 10 + Q];
  gateh<ML_[L][Q], MR_[L][Q], HR_[L][Q]>(Hr, Hi, sgnv[SIX[L - 1][Q]], a30, a28, a20, cp);
}

// per-qubit encoded+layer0 2-vector: (alpha,beta) = U0q * (cos, sin)
// native v_sin/v_cos: |xq*0.5| <~ 3 rad, well within native range
__device__ __forceinline__ void enc2(const float4 g, float xq,
                                     float& ar, float& ai, float& br, float& bi) {
  const float t = xq * 0.5f;
  const float sq = __sinf(t), cq = __cosf(t);
  ar = g.x * cq - g.z * sq;
  ai = g.y * cq + g.w * sq;
  br = g.z * cq + g.x * sq;
  bi = g.w * cq - g.y * sq;
}
__device__ __forceinline__ void cmul(float& zr, float& zi,
                                     float xr, float xi, float yr, float yi) {
  zr = xr * yr - xi * yi;
  zi = xr * yi + xi * yr;
}

// K0: fused SU(2) RY*RX*RZ per (layer,qubit); also zeroes the stats accumulators
__global__ void coef_kernel(const float* __restrict__ params, float* __restrict__ coef,
                            unsigned* __restrict__ cph, float* __restrict__ stats) {
  int g = threadIdx.x;
  if (g < 20) stats[g] = 0.f;
  if (g < 30) {
    float t0 = params[g * 3 + 0] * 0.5f;
    float t1 = params[g * 3 + 1] * 0.5f;
    float t2 = params[g * 3 + 2] * 0.5f;
    float sa, ca, s2, c2, s3, c3;
    __sincosf(t0, &sa, &ca);
    __sincosf(t1, &s2, &c2);
    __sincosf(t2, &s3, &c3);
    float A = c3 * c2, Bv = s3 * s2, C = s3 * c2, D = c3 * s2;
    float wr = A * ca + Bv * sa;
    float wi = Bv * ca - A * sa;
    float vr = C * ca - D * sa;
    float vi = -(C * sa + D * ca);
    coef[g * 4 + 0] = wr;
    coef[g * 4 + 1] = wi;
    coef[g * 4 + 2] = vr;
    coef[g * 4 + 3] = vi;
    if (g >= 10) {
      int gi = g - 10;
      cph[gi * 4 + 0] = h2u(hpack(wr, wr));
      cph[gi * 4 + 1] = h2u(hpack(wi, wi));
      cph[gi * 4 + 2] = h2u(hpack(vr, vr));
      cph[gi * 4 + 3] = h2u(hpack(vi, vi));
    }
  }
}

// K1: one wave64 per sample; 1024 amps as 16 packed-f16 VGPRs; fused BN stats.
__global__ __launch_bounds__(256) void circuit_kernel(const float* __restrict__ x,
                                                      const float* __restrict__ coef,
                                                      const uint4* __restrict__ cph,
                                                      float* __restrict__ out,
                                                      float* __restrict__ stats) {
  const int lane = threadIdx.x & 63;
  const int wv = threadIdx.x >> 6;
  const int wid = __builtin_amdgcn_readfirstlane(
      (int)((blockIdx.x * blockDim.x + threadIdx.x) >> 6));
  const float4* cg = (const float4*)coef;

  const int a30 = (lane ^ 0x30) << 2;
  const int a28 = (lane ^ 0x28) << 2;
  const int a20 = (lane ^ 0x20) << 2;

  // precomputed lane-parity sign words for the 12 distinct HL masks
  unsigned sgnv[12];
  #pragma unroll
  for (int k = 0; k < 12; ++k)
    sgnv[k] = (__builtin_popcount(lane & SMASK[k]) & 1) ? 0u : 0x80008000u;

  // ---- encoding + layer-0 folded: f32 progressive tensor-product build ----
  const float* xrow = x + wid * NQ;
  float lr, li;
  {
    float ar, ai, br, bi;
    enc2(cg[0], xrow[0], ar, ai, br, bi);
    lr = (lane & 32) ? br : ar;
    li = (lane & 32) ? bi : ai;
  }
  #pragma unroll
  for (int q = 1; q < 6; ++q) {
    float ar, ai, br, bi;
    enc2(cg[q], xrow[q], ar, ai, br, bi);
    const int bit = 1 << (5 - q);
    const float tr = (lane & bit) ? br : ar;
    const float ti = (lane & bit) ? bi : ai;
    const float nr = lr * tr - li * ti;
    const float ni = lr * ti + li * tr;
    lr = nr; li = ni;
  }
  float sr[16], si[16];
  {
    float ar, ai, br, bi;
    float t2r[2], t2i[2], t4r[4], t4i[4], t8r[8], t8i[8];
    enc2(cg[6], xrow[6], ar, ai, br, bi);
    cmul(t2r[0], t2i[0], lr, li, ar, ai);
    cmul(t2r[1], t2i[1], lr, li, br, bi);
    enc2(cg[7], xrow[7], ar, ai, br, bi);
    #pragma unroll
    for (int j = 0; j < 2; ++j) {
      cmul(t4r[2*j+0], t4i[2*j+0], t2r[j], t2i[j], ar, ai);
      cmul(t4r[2*j+1], t4i[2*j+1], t2r[j], t2i[j], br, bi);
    }
    enc2(cg[8], xrow[8], ar, ai, br, bi);
    #pragma unroll
    for (int j = 0; j < 4; ++j) {
      cmul(t8r[2*j+0], t8i[2*j+0], t4r[j], t4i[j], ar, ai);
      cmul(t8r[2*j+1], t8i[2*j+1], t4r[j], t4i[j], br, bi);
    }
    enc2(cg[9], xrow[9], ar, ai, br, bi);
    #pragma unroll
    for (int j = 0; j < 8; ++j) {
      cmul(sr[2*j+0], si[2*j+0], t8r[j], t8i[j], ar, ai);
      cmul(sr[2*j+1], si[2*j+1], t8r[j], t8i[j], br, bi);
    }
  }
  // pack pairs (r, r|8)
  __half2 Hr[8], Hi[8];
  #pragma unroll
  for (int j = 0; j < 8; ++j) {
    Hr[j] = hpack(sr[j], sr[j | 8]);
    Hi[j] = hpack(si[j], si[j | 8]);
  }

  // ---- layers 1,2 fused rotations (packed); CNOT chains free ----
  rotgh<1,0>(cph,Hr,Hi,sgnv,a30,a28,a20); rotgh<1,1>(cph,Hr,Hi,sgnv,a30,a28,a20);
  rotgh<1,2>(cph,Hr,Hi,sgnv,a30,a28,a20); rotgh<1,3>(cph,Hr,Hi,sgnv,a30,a28,a20);
  rotgh<1,4>(cph,Hr,Hi,sgnv,a30,a28,a20); rotgh<1,5>(cph,Hr,Hi,sgnv,a30,a28,a20);
  rotgh<1,6>(cph,Hr,Hi,sgnv,a30,a28,a20); rotgh<1,7>(cph,Hr,Hi,sgnv,a30,a28,a20);
  rotgh<1,8>(cph,Hr,Hi,sgnv,a30,a28,a20); rotgh<1,9>(cph,Hr,Hi,sgnv,a30,a28,a20);

  rotgh<2,0>(cph,Hr,Hi,sgnv,a30,a28,a20); rotgh<2,1>(cph,Hr,Hi,sgnv,a30,a28,a20);
  rotgh<2,2>(cph,Hr,Hi,sgnv,a30,a28,a20); rotgh<2,3>(cph,Hr,Hi,sgnv,a30,a28,a20);
  rotgh<2,4>(cph,Hr,Hi,sgnv,a30,a28,a20); rotgh<2,5>(cph,Hr,Hi,sgnv,a30,a28,a20);
  rotgh<2,6>(cph,Hr,Hi,sgnv,a30,a28,a20); rotgh<2,7>(cph,Hr,Hi,sgnv,a30,a28,a20);
  rotgh<2,8>(cph,Hr,Hi,sgnv,a30,a28,a20); rotgh<2,9>(cph,Hr,Hi,sgnv,a30,a28,a20);

  // ---- packed epilogue: 4 packed Walsh accumulators ----
  __half2 A0 = u2h(0u), A1 = A0, A2 = A0, A3 = A0;
  #pragma unroll
  for (int j = 0; j < 8; ++j) {
    const __half2 P = __hfma2(Hr[j], Hr[j], __hmul2(Hi[j], Hi[j]));
    A0 = __hadd2(A0, P);
    A1 = par4(j & 4) ? __hsub2(A1, P) : __hadd2(A1, P);
    A2 = par4(j & 6) ? __hsub2(A2, P) : __hadd2(A2, P);
    A3 = par4(j & 3) ? __hsub2(A3, P) : __hadd2(A3, P);
  }
  const float a0lo = __half2float(__low2half(A0)), a0hi = __half2float(__high2half(A0));
  const float a1lo = __half2float(__low2half(A1)), a1hi = __half2float(__high2half(A1));
  const float a2lo = __half2float(__low2half(A2)), a2hi = __half2float(__high2half(A2));
  const float a3lo = __half2float(__low2half(A3)), a3hi = __half2float(__high2half(A3));
  const float tot = a0lo + a0hi;
  const float s8  = a0lo - a0hi;   // reg mask 0x8
  const float sc  = a1lo - a1hi;   // reg mask 0xC
  const float s6  = a2lo + a2hi;   // reg mask 0x6
  const float s3  = a3lo + a3hi;   // reg mask 0x3

  const float S[10] = {tot, tot, tot, tot, tot, tot, s8, sc, s6, s3};
  __half2 E[5];
  #pragma unroll
  for (int k = 0; k < 5; ++k) {
    float ea = S[2 * k], eb = S[2 * k + 1];
    ea = (__builtin_popcount(lane & EHL[2 * k]) & 1) ? -ea : ea;
    eb = (__builtin_popcount(lane & EHL[2 * k + 1]) & 1) ? -eb : eb;
    E[k] = hpack(ea, eb);
  }
  #pragma unroll
  for (int k = 0; k < 5; ++k) {
    E[k] = __hadd2(E[k], shufh<0x20>(E[k], a30, a28, a20));
    E[k] = __hadd2(E[k], shufh<0x10>(E[k], a30, a28, a20));
    E[k] = __hadd2(E[k], shufh<0x08>(E[k], a30, a28, a20));
    E[k] = __hadd2(E[k], shufh<0x04>(E[k], a30, a28, a20));
    E[k] = __hadd2(E[k], shufh<0x02>(E[k], a30, a28, a20));
    E[k] = __hadd2(E[k], shufh<0x01>(E[k], a30, a28, a20));
  }

  // ---- store + fused BN stats (block reduce -> 20 atomics/block) ----
  __shared__ float red[4][20];
  if (lane == 0) {
    #pragma unroll
    for (int k = 0; k < 5; ++k) {
      const float ea = __half2float(__low2half(E[k]));
      const float eb = __half2float(__high2half(E[k]));
      out[wid * NQ + 2 * k]     = ea;
      out[wid * NQ + 2 * k + 1] = eb;
      red[wv][2 * k]          = ea;
      red[wv][2 * k + 1]      = eb;
      red[wv][10 + 2 * k]     = ea * ea;
      red[wv][10 + 2 * k + 1] = eb * eb;
    }
  }
  __syncthreads();
  const int tid = threadIdx.x;
  if (tid < 20) {
    float ssum = red[0][tid] + red[1][tid] + red[2][tid] + red[3][tid];
    atomicAdd(&stats[tid], ssum);
  }
}

// K2: BatchNorm apply; finalizes mean/rstd from fused sums per thread.
__global__ __launch_bounds__(256) void bn_kernel(float* __restrict__ out,
                                                 const float* __restrict__ stats,
                                                 const float* __restrict__ gamma,
                                                 const float* __restrict__ beta) {
  int i = blockIdx.x * 256 + threadIdx.x;
  if (i < NSAMP * NQ) {
    int q = i % NQ;
    float mean = stats[q] * (1.f / NSAMP);
    float var = stats[10 + q] * (1.f / NSAMP) - mean * mean;
    if (var < 0.f) var = 0.f;
    float rstd = rsqrtf(var + BN_EPS);
    float v = out[i];
    out[i] = gamma[q] * (v - mean) * rstd + beta[q];
  }
}

extern "C" void kernel_launch(void* const* d_in, const int* in_sizes, int n_in,
                              void* d_out, int out_size, void* d_ws, size_t ws_size,
                              hipStream_t stream) {
  const float* x      = (const float*)d_in[0];
  const float* params = (const float*)d_in[1];
  const float* gamma  = (const float*)d_in[2];
  const float* beta   = (const float*)d_in[3];
  float* out = (float*)d_out;
  float* stats = (float*)d_ws;                        // [0..9]=sum, [10..19]=sum^2
  float* coef = (float*)d_ws + 32;                    // 30 gates * 4 f32
  unsigned* cph = (unsigned*)((float*)d_ws + 160);    // 20 gates * 4 packed (16B-aligned)

  coef_kernel<<<1, 32, 0, stream>>>(params, coef, cph, stats);
  circuit_kernel<<<NSAMP / 4, 256, 0, stream>>>(x, coef, (const uint4*)cph, out, stats);
  bn_kernel<<<(NSAMP * NQ + 255) / 256, 256, 0, stream>>>(out, stats, gamma, beta);
}

// Round 12
// 66.473 us; speedup vs baseline: 10.9373x; 1.0671x over previous
//
#include <hip/hip_runtime.h>
#include <hip/hip_fp16.h>

#define NQ 10
#define NSAMP 16384
#define BN_EPS 1e-5f
#define SGN 0x80008000u

// ---------------- packed f16 helpers: h2 = (sample A, sample B) ----------------
union H2U { __half2 h; unsigned u; };
__device__ __forceinline__ __half2 u2h(unsigned u) { H2U t; t.u = u; return t.h; }
__device__ __forceinline__ unsigned h2u(__half2 h) { H2U t; t.h = h; return t.u; }
__device__ __forceinline__ __half2 hpack(float lo, float hi) {
  return __floats2half2_rn(lo, hi);
}

// masks < 0x20: ds_swizzle immediate xor; >= 0x20: ds_bpermute w/ precomputed addr
template<int M>
__device__ __forceinline__ unsigned shufu(unsigned v, int a30, int a28, int a20) {
  if constexpr (M < 32) {
    return (unsigned)__builtin_amdgcn_ds_swizzle((int)v, (M << 10) | 0x1F);
  } else {
    const int addr = (M == 0x30) ? a30 : (M == 0x28) ? a28 : a20;
    return (unsigned)__builtin_amdgcn_ds_bpermute(addr, (int)v);
  }
}
template<int M>
__device__ __forceinline__ __half2 shufh(__half2 v, int a30, int a28, int a20) {
  return u2h(shufu<M>(h2u(v), a30, a28, a20));
}

// -------- mask tables (deferred CNOT-chain relabeling) — trace-verified R4-R11 --------
// Index bit b (9..0) = wire (9-b). Lane holds bits 9..4, regs bits 3..0.
// 16 h2 regs: reg index r = stored index bits 3..0; h2 halves = two samples.
constexpr int ML_[3][10] = {
  {0x20,0x10,0x08,0x04,0x02,0x01, 0,   0,   0,   0},
  {0x30,0x18,0x0C,0x06,0x03,0x01, 0,   0,   0,   0},
  {0x28,0x14,0x0A,0x05,0x02,0x01, 0,   0,   0,   0}};
constexpr int MR_[3][10] = {
  {0,0,0,0,0,0,   0x8,0x4,0x2,0x1},
  {0,0,0,0,0,0x8, 0xC,0x6,0x3,0x1},
  {0,0,0,0,0x8,0x4,0xA,0x5,0x2,0x1}};
constexpr int HR_[3][10] = {
  {0,0,0,0,0,0, 0x8,0x4,0x2,0x1},
  {0,0,0,0,0,0, 0x8,0xC,0xE,0xF},
  {0,0,0,0,0,0, 0x8,0x4,0xA,0x5}};
// Epilogue sign masks (row b of C^{-3}), trace-verified in R4.
constexpr int EHL[10] = {0x20,0x30,0x18,0x0C,0x26,0x33,0x19,0x0C,0x26,0x33};
// Epilogue reg-parity masks for q6..9: 0x8, 0xC, 0x6, 0x3 (accumulated directly).

// distinct HL masks for layers 1,2 -> precomputed sign-word index
constexpr int SMASK[12] = {0x20,0x30,0x38,0x3C,0x3E,0x3F, 0x20,0x10,0x28,0x14,0x2A,0x15};
constexpr int SIX[2][10] = {{0,1,2,3,4,5,5,5,5,5}, {6,7,8,9,10,11,10,11,10,11}};

constexpr int hibit4(int m) {
  return m >= 8 ? 8 : (m >= 4 ? 4 : (m >= 2 ? 2 : (m ? 1 : 0)));
}
constexpr bool par4(int v) { return ((v >> 3 & 1) ^ (v >> 2 & 1) ^ (v >> 1 & 1) ^ (v & 1)) != 0; }

// amp update: 3 pk-FMA + 1 pk-mul per component
__device__ __forceinline__ void updh(__half2& ar, __half2& ai, __half2 br, __half2 bi,
                                     __half2 WR, __half2 AWI, __half2 NAWI,
                                     __half2 AVR, __half2 VI, __half2 NVI) {
  const __half2 a0r = ar, a0i = ai;
  ar = __hfma2(WR, a0r, __hfma2(AWI, a0i, __hfma2(AVR, br, __hmul2(NVI, bi))));
  ai = __hfma2(WR, a0i, __hfma2(NAWI, a0r, __hfma2(AVR, bi, __hmul2(VI, br))));
}

// SU(2) gate on 16-h2 state (both samples share all signs).
// sgnw = lane-parity sign word (0 if hi-parity lane, else 0x80008000).
template<int ML, int MR, int HR>
__device__ __forceinline__ void gateh(__half2* __restrict__ Hr, __half2* __restrict__ Hi,
                                      unsigned sgnw, int a30, int a28, int a20, uint4 cp) {
  const unsigned swi = cp.y ^ sgnw;
  const unsigned svr = cp.z ^ sgnw;
  const __half2 WR  = u2h(cp.x);
  const __half2 VI  = u2h(cp.w);
  const __half2 NVI = u2h(cp.w ^ SGN);
  const __half2 WI0 = u2h(swi);            // awi for reg-parity 0
  const __half2 WI1 = u2h(swi ^ SGN);      // awi for reg-parity 1 (== -WI0)
  const __half2 VR0 = u2h(svr);
  const __half2 VR1 = u2h(svr ^ SGN);

  if constexpr (MR == 0) {                 // pure lane-bit gate
    #pragma unroll
    for (int r = 0; r < 16; ++r) {
      const __half2 br = shufh<ML>(Hr[r], a30, a28, a20);
      const __half2 bi = shufh<ML>(Hi[r], a30, a28, a20);
      const bool p = par4(r & HR);
      updh(Hr[r], Hi[r], br, bi, WR, p ? WI1 : WI0, p ? WI0 : WI1,
           p ? VR1 : VR0, VI, NVI);
    }
  } else {                                 // reg pair (+ maybe lane)
    constexpr int HB = hibit4(MR);
    #pragma unroll
    for (int r = 0; r < 16; ++r) {
      if (!(r & HB)) {
        const int r2 = r ^ MR;
        __half2 b0r, b0i, b1r, b1i;
        if constexpr (ML != 0) {
          b0r = shufh<ML>(Hr[r2], a30, a28, a20); b0i = shufh<ML>(Hi[r2], a30, a28, a20);
          b1r = shufh<ML>(Hr[r],  a30, a28, a20); b1i = shufh<ML>(Hi[r],  a30, a28, a20);
        } else {
          b0r = Hr[r2]; b0i = Hi[r2]; b1r = Hr[r]; b1i = Hi[r];
        }
        const bool pa = par4(r & HR);
        updh(Hr[r], Hi[r], b0r, b0i, WR, pa ? WI1 : WI0, pa ? WI0 : WI1,
             pa ? VR1 : VR0, VI, NVI);
        const bool pb = par4(r2 & HR);
        updh(Hr[r2], Hi[r2], b1r, b1i, WR, pb ? WI1 : WI0, pb ? WI0 : WI1,
             pb ? VR1 : VR0, VI, NVI);
      }
    }
  }
}

template<int L, int Q>
__device__ __forceinline__ void rotgh(const uint4* __restrict__ cph,
                                      __half2* Hr, __half2* Hi,
                                      const unsigned* __restrict__ sgnv,
                                      int a30, int a28, int a20) {
  const uint4 cp = cph[(L - 1) * 10 + Q];
  gateh<ML_[L][Q], MR_[L][Q], HR_[L][Q]>(Hr, Hi, sgnv[SIX[L - 1][Q]], a30, a28, a20, cp);
}

// per-qubit encoded+layer0 2-vector: (alpha,beta) = U0q * (cos, sin)
__device__ __forceinline__ void enc2(const float4 g, float xq,
                                     float& ar, float& ai, float& br, float& bi) {
  const float t = xq * 0.5f;
  const float sq = __sinf(t), cq = __cosf(t);
  ar = g.x * cq - g.z * sq;
  ai = g.y * cq + g.w * sq;
  br = g.z * cq + g.x * sq;
  bi = g.w * cq - g.y * sq;
}
__device__ __forceinline__ void cmul(float& zr, float& zi,
                                     float xr, float xi, float yr, float yi) {
  zr = xr * yr - xi * yi;
  zi = xr * yi + xi * yr;
}

// f32 progressive tensor-product build (encoding + folded layer-0) for one sample
__device__ __forceinline__ void build_state(const float* __restrict__ xrow,
                                            const float4* __restrict__ cg,
                                            int lane, float* __restrict__ sr,
                                            float* __restrict__ si) {
  float lr, li;
  {
    float ar, ai, br, bi;
    enc2(cg[0], xrow[0], ar, ai, br, bi);
    lr = (lane & 32) ? br : ar;
    li = (lane & 32) ? bi : ai;
  }
  #pragma unroll
  for (int q = 1; q < 6; ++q) {
    float ar, ai, br, bi;
    enc2(cg[q], xrow[q], ar, ai, br, bi);
    const int bit = 1 << (5 - q);
    const float tr = (lane & bit) ? br : ar;
    const float ti = (lane & bit) ? bi : ai;
    const float nr = lr * tr - li * ti;
    const float ni = lr * ti + li * tr;
    lr = nr; li = ni;
  }
  float ar, ai, br, bi;
  float t2r[2], t2i[2], t4r[4], t4i[4], t8r[8], t8i[8];
  enc2(cg[6], xrow[6], ar, ai, br, bi);
  cmul(t2r[0], t2i[0], lr, li, ar, ai);
  cmul(t2r[1], t2i[1], lr, li, br, bi);
  enc2(cg[7], xrow[7], ar, ai, br, bi);
  #pragma unroll
  for (int j = 0; j < 2; ++j) {
    cmul(t4r[2*j+0], t4i[2*j+0], t2r[j], t2i[j], ar, ai);
    cmul(t4r[2*j+1], t4i[2*j+1], t2r[j], t2i[j], br, bi);
  }
  enc2(cg[8], xrow[8], ar, ai, br, bi);
  #pragma unroll
  for (int j = 0; j < 4; ++j) {
    cmul(t8r[2*j+0], t8i[2*j+0], t4r[j], t4i[j], ar, ai);
    cmul(t8r[2*j+1], t8i[2*j+1], t4r[j], t4i[j], br, bi);
  }
  enc2(cg[9], xrow[9], ar, ai, br, bi);
  #pragma unroll
  for (int j = 0; j < 8; ++j) {
    cmul(sr[2*j+0], si[2*j+0], t8r[j], t8i[j], ar, ai);
    cmul(sr[2*j+1], si[2*j+1], t8r[j], t8i[j], br, bi);
  }
}

// K0: fused SU(2) RY*RX*RZ per (layer,qubit); also zeroes the stats accumulators
__global__ void coef_kernel(const float* __restrict__ params, float* __restrict__ coef,
                            unsigned* __restrict__ cph, float* __restrict__ stats) {
  int g = threadIdx.x;
  if (g < 20) stats[g] = 0.f;
  if (g < 30) {
    float t0 = params[g * 3 + 0] * 0.5f;
    float t1 = params[g * 3 + 1] * 0.5f;
    float t2 = params[g * 3 + 2] * 0.5f;
    float sa, ca, s2, c2, s3, c3;
    __sincosf(t0, &sa, &ca);
    __sincosf(t1, &s2, &c2);
    __sincosf(t2, &s3, &c3);
    float A = c3 * c2, Bv = s3 * s2, C = s3 * c2, D = c3 * s2;
    float wr = A * ca + Bv * sa;
    float wi = Bv * ca - A * sa;
    float vr = C * ca - D * sa;
    float vi = -(C * sa + D * ca);
    coef[g * 4 + 0] = wr;
    coef[g * 4 + 1] = wi;
    coef[g * 4 + 2] = vr;
    coef[g * 4 + 3] = vi;
    if (g >= 10) {
      int gi = g - 10;
      cph[gi * 4 + 0] = h2u(hpack(wr, wr));
      cph[gi * 4 + 1] = h2u(hpack(wi, wi));
      cph[gi * 4 + 2] = h2u(hpack(vr, vr));
      cph[gi * 4 + 3] = h2u(hpack(vi, vi));
    }
  }
}

// K1: one wave64 per TWO samples (h2 lo = sample A, hi = sample B); fused BN stats.
__global__ __launch_bounds__(256) void circuit_kernel(const float* __restrict__ x,
                                                      const float* __restrict__ coef,
                                                      const uint4* __restrict__ cph,
                                                      float* __restrict__ out,
                                                      float* __restrict__ stats) {
  const int lane = threadIdx.x & 63;
  const int wv = threadIdx.x >> 6;
  const int wid = __builtin_amdgcn_readfirstlane(
      (int)((blockIdx.x * blockDim.x + threadIdx.x) >> 6));
  const float4* cg = (const float4*)coef;

  const int a30 = (lane ^ 0x30) << 2;
  const int a28 = (lane ^ 0x28) << 2;
  const int a20 = (lane ^ 0x20) << 2;

  // precomputed lane-parity sign words for the 12 distinct HL masks
  unsigned sgnv[12];
  #pragma unroll
  for (int k = 0; k < 12; ++k)
    sgnv[k] = (__builtin_popcount(lane & SMASK[k]) & 1) ? 0u : SGN;

  // ---- build two samples' product states (f32), pack into h2 halves ----
  const int sA = wid * 2, sB = wid * 2 + 1;
  float srA[16], siA[16], srB[16], siB[16];
  build_state(x + sA * NQ, cg, lane, srA, siA);
  build_state(x + sB * NQ, cg, lane, srB, siB);
  __half2 Hr[16], Hi[16];
  #pragma unroll
  for (int r = 0; r < 16; ++r) {
    Hr[r] = hpack(srA[r], srB[r]);
    Hi[r] = hpack(siA[r], siB[r]);
  }

  // ---- layers 1,2 fused rotations (both samples per pk op); CNOTs free ----
  rotgh<1,0>(cph,Hr,Hi,sgnv,a30,a28,a20); rotgh<1,1>(cph,Hr,Hi,sgnv,a30,a28,a20);
  rotgh<1,2>(cph,Hr,Hi,sgnv,a30,a28,a20); rotgh<1,3>(cph,Hr,Hi,sgnv,a30,a28,a20);
  rotgh<1,4>(cph,Hr,Hi,sgnv,a30,a28,a20); rotgh<1,5>(cph,Hr,Hi,sgnv,a30,a28,a20);
  rotgh<1,6>(cph,Hr,Hi,sgnv,a30,a28,a20); rotgh<1,7>(cph,Hr,Hi,sgnv,a30,a28,a20);
  rotgh<1,8>(cph,Hr,Hi,sgnv,a30,a28,a20); rotgh<1,9>(cph,Hr,Hi,sgnv,a30,a28,a20);

  rotgh<2,0>(cph,Hr,Hi,sgnv,a30,a28,a20); rotgh<2,1>(cph,Hr,Hi,sgnv,a30,a28,a20);
  rotgh<2,2>(cph,Hr,Hi,sgnv,a30,a28,a20); rotgh<2,3>(cph,Hr,Hi,sgnv,a30,a28,a20);
  rotgh<2,4>(cph,Hr,Hi,sgnv,a30,a28,a20); rotgh<2,5>(cph,Hr,Hi,sgnv,a30,a28,a20);
  rotgh<2,6>(cph,Hr,Hi,sgnv,a30,a28,a20); rotgh<2,7>(cph,Hr,Hi,sgnv,a30,a28,a20);
  rotgh<2,8>(cph,Hr,Hi,sgnv,a30,a28,a20); rotgh<2,9>(cph,Hr,Hi,sgnv,a30,a28,a20);

  // ---- epilogue: 5 Walsh sums, both samples at once (h2 halves) ----
  __half2 T = u2h(0u), S8 = T, SC = T, S6 = T, S3 = T;
  #pragma unroll
  for (int r = 0; r < 16; ++r) {
    const __half2 P = __hfma2(Hr[r], Hr[r], __hmul2(Hi[r], Hi[r]));
    T = __hadd2(T, P);
    S8 = par4(r & 0x8) ? __hsub2(S8, P) : __hadd2(S8, P);
    SC = par4(r & 0xC) ? __hsub2(SC, P) : __hadd2(SC, P);
    S6 = par4(r & 0x6) ? __hsub2(S6, P) : __hadd2(S6, P);
    S3 = par4(r & 0x3) ? __hsub2(S3, P) : __hadd2(S3, P);
  }
  const __half2 S[10] = {T, T, T, T, T, T, S8, SC, S6, S3};
  __half2 e[10];
  #pragma unroll
  for (int q = 0; q < 10; ++q) {
    const bool neg = (__builtin_popcount(lane & EHL[q]) & 1) != 0;
    e[q] = u2h(h2u(S[q]) ^ (neg ? SGN : 0u));
  }
  #pragma unroll
  for (int q = 0; q < 10; ++q) {
    e[q] = __hadd2(e[q], shufh<0x20>(e[q], a30, a28, a20));
    e[q] = __hadd2(e[q], shufh<0x10>(e[q], a30, a28, a20));
    e[q] = __hadd2(e[q], shufh<0x08>(e[q], a30, a28, a20));
    e[q] = __hadd2(e[q], shufh<0x04>(e[q], a30, a28, a20));
    e[q] = __hadd2(e[q], shufh<0x02>(e[q], a30, a28, a20));
    e[q] = __hadd2(e[q], shufh<0x01>(e[q], a30, a28, a20));
  }

  // ---- store + fused BN stats (block reduce -> 20 atomics/block) ----
  __shared__ float red[4][20];
  if (lane == 0) {
    #pragma unroll
    for (int q = 0; q < 10; ++q) {
      const float ea = __half2float(__low2half(e[q]));
      const float eb = __half2float(__high2half(e[q]));
      out[sA * NQ + q] = ea;
      out[sB * NQ + q] = eb;
      red[wv][q]      = ea + eb;
      red[wv][10 + q] = ea * ea + eb * eb;
    }
  }
  __syncthreads();
  const int tid = threadIdx.x;
  if (tid < 20) {
    float ssum = red[0][tid] + red[1][tid] + red[2][tid] + red[3][tid];
    atomicAdd(&stats[tid], ssum);
  }
}

// K2: BatchNorm apply; finalizes mean/rstd from fused sums per thread.
__global__ __launch_bounds__(256) void bn_kernel(float* __restrict__ out,
                                                 const float* __restrict__ stats,
                                                 const float* __restrict__ gamma,
                                                 const float* __restrict__ beta) {
  int i = blockIdx.x * 256 + threadIdx.x;
  if (i < NSAMP * NQ) {
    int q = i % NQ;
    float mean = stats[q] * (1.f / NSAMP);
    float var = stats[10 + q] * (1.f / NSAMP) - mean * mean;
    if (var < 0.f) var = 0.f;
    float rstd = rsqrtf(var + BN_EPS);
    float v = out[i];
    out[i] = gamma[q] * (v - mean) * rstd + beta[q];
  }
}

extern "C" void kernel_launch(void* const* d_in, const int* in_sizes, int n_in,
                              void* d_out, int out_size, void* d_ws, size_t ws_size,
                              hipStream_t stream) {
  const float* x      = (const float*)d_in[0];
  const float* params = (const float*)d_in[1];
  const float* gamma  = (const float*)d_in[2];
  const float* beta   = (const float*)d_in[3];
  float* out = (float*)d_out;
  float* stats = (float*)d_ws;                        // [0..9]=sum, [10..19]=sum^2
  float* coef = (float*)d_ws + 32;                    // 30 gates * 4 f32
  unsigned* cph = (unsigned*)((float*)d_ws + 160);    // 20 gates * 4 packed (16B-aligned)

  coef_kernel<<<1, 32, 0, stream>>>(params, coef, cph, stats);
  circuit_kernel<<<NSAMP / 8, 256, 0, stream>>>(x, coef, (const uint4*)cph, out, stats);
  bn_kernel<<<(NSAMP * NQ + 255) / 256, 256, 0, stream>>>(out, stats, gamma, beta);
}